// Round 1
// baseline (103.411 us; speedup 1.0000x reference)
//
#include <hip/hip_runtime.h>
#include <stdint.h>

// BiasedFeatureDropout: out = x * mask * 1.25, mask from JAX threefry PRNG
// (partitionable path: bits[i] = o0^o1 of threefry2x32(key=(0,1), (0, i)))
// keep iff u < (channel<32 ? 0.2f : 0.8f), u = bitcast((bits>>9)|0x3F800000)-1

#define ROTL(x, n) (((x) << (n)) | ((x) >> (32 - (n))))

__device__ __forceinline__ uint32_t threefry_bits(uint32_t i) {
    // key = (0, 1): ks0 = 0, ks1 = 1, ks2 = 0 ^ 1 ^ 0x1BD11BDA = 0x1BD11BDB
    const uint32_t ks0 = 0u, ks1 = 1u, ks2 = 0x1BD11BDBu;
    uint32_t x0 = ks0;          // count_hi = 0
    uint32_t x1 = i + ks1;      // count_lo = i
    // rounds 1-4: rot [13,15,26,6]
    x0 += x1; x1 = ROTL(x1, 13); x1 ^= x0;
    x0 += x1; x1 = ROTL(x1, 15); x1 ^= x0;
    x0 += x1; x1 = ROTL(x1, 26); x1 ^= x0;
    x0 += x1; x1 = ROTL(x1,  6); x1 ^= x0;
    x0 += ks1; x1 += ks2 + 1u;
    // rounds 5-8: rot [17,29,16,24]
    x0 += x1; x1 = ROTL(x1, 17); x1 ^= x0;
    x0 += x1; x1 = ROTL(x1, 29); x1 ^= x0;
    x0 += x1; x1 = ROTL(x1, 16); x1 ^= x0;
    x0 += x1; x1 = ROTL(x1, 24); x1 ^= x0;
    x0 += ks2; x1 += ks0 + 2u;
    // rounds 9-12: rot [13,15,26,6]
    x0 += x1; x1 = ROTL(x1, 13); x1 ^= x0;
    x0 += x1; x1 = ROTL(x1, 15); x1 ^= x0;
    x0 += x1; x1 = ROTL(x1, 26); x1 ^= x0;
    x0 += x1; x1 = ROTL(x1,  6); x1 ^= x0;
    x0 += ks0; x1 += ks1 + 3u;
    // rounds 13-16: rot [17,29,16,24]
    x0 += x1; x1 = ROTL(x1, 17); x1 ^= x0;
    x0 += x1; x1 = ROTL(x1, 29); x1 ^= x0;
    x0 += x1; x1 = ROTL(x1, 16); x1 ^= x0;
    x0 += x1; x1 = ROTL(x1, 24); x1 ^= x0;
    x0 += ks1; x1 += ks2 + 4u;
    // rounds 17-20: rot [13,15,26,6]
    x0 += x1; x1 = ROTL(x1, 13); x1 ^= x0;
    x0 += x1; x1 = ROTL(x1, 15); x1 ^= x0;
    x0 += x1; x1 = ROTL(x1, 26); x1 ^= x0;
    x0 += x1; x1 = ROTL(x1,  6); x1 ^= x0;
    x0 += ks2; x1 += ks0 + 5u;
    return x0 ^ x1;   // partitionable 32-bit path: bits = o0 ^ o1
}

__global__ __launch_bounds__(256) void BiasedFeatureDropout_kernel(
        const float4* __restrict__ x, float4* __restrict__ out, int n4) {
    int t = blockIdx.x * blockDim.x + threadIdx.x;
    if (t >= n4) return;

    const uint32_t CHW   = 802816u;   // 256*56*56
    const uint32_t BIASE = 100352u;   // 32*56*56

    uint32_t base = (uint32_t)t * 4u;
    // base % 4 == 0 and CHW,BIASE % 4 == 0  ->  all 4 elems share the verdict
    uint32_t rem = base % CHW;
    float thresh = (rem < BIASE) ? 0.2f : 0.8f;

    float4 v = x[t];
    float vi[4] = {v.x, v.y, v.z, v.w};
    float ro[4];
    #pragma unroll
    for (int k = 0; k < 4; ++k) {
        uint32_t bits = threefry_bits(base + (uint32_t)k);
        float u = __uint_as_float((bits >> 9) | 0x3F800000u) - 1.0f;
        ro[k] = (u < thresh) ? vi[k] * 1.25f : 0.0f;
    }
    out[t] = make_float4(ro[0], ro[1], ro[2], ro[3]);
}

extern "C" void kernel_launch(void* const* d_in, const int* in_sizes, int n_in,
                              void* d_out, int out_size, void* d_ws, size_t ws_size,
                              hipStream_t stream) {
    const float* x = (const float*)d_in[0];
    float* out = (float*)d_out;
    int n = out_size;              // 51,380,224 (divisible by 4)
    int n4 = n / 4;
    int block = 256;
    int grid = (n4 + block - 1) / block;
    BiasedFeatureDropout_kernel<<<grid, block, 0, stream>>>(
        (const float4*)x, (float4*)out, n4);
}

// Round 3
// 94.562 us; speedup vs baseline: 1.0936x; 1.0936x over previous
//
#include <hip/hip_runtime.h>
#include <stdint.h>

// BiasedFeatureDropout: out = x * mask * 1.25, mask from JAX threefry PRNG
// (partitionable path: bits[i] = o0^o1 of threefry2x32(key=(0,1), (0, i)))
// keep iff bits < T*512, T = 1677722 (bias ch<32) / 6710887 (regular)
// (integer form of u < 0.2f / 0.8f with u = (bits>>9)*2^-23, exact)

typedef float v4f __attribute__((ext_vector_type(4)));

#define ROTL(x, n) (((x) << (n)) | ((x) >> (32 - (n))))

__device__ __forceinline__ uint32_t threefry_bits(uint32_t i) {
    // key = (0, 1): ks0 = 0, ks1 = 1, ks2 = 0 ^ 1 ^ 0x1BD11BDA = 0x1BD11BDB
    const uint32_t ks0 = 0u, ks1 = 1u, ks2 = 0x1BD11BDBu;
    uint32_t x0 = ks0;          // count_hi = 0
    uint32_t x1 = i + ks1;      // count_lo = i
    // rounds 1-4: rot [13,15,26,6]
    x0 += x1; x1 = ROTL(x1, 13); x1 ^= x0;
    x0 += x1; x1 = ROTL(x1, 15); x1 ^= x0;
    x0 += x1; x1 = ROTL(x1, 26); x1 ^= x0;
    x0 += x1; x1 = ROTL(x1,  6); x1 ^= x0;
    x0 += ks1; x1 += ks2 + 1u;
    // rounds 5-8: rot [17,29,16,24]
    x0 += x1; x1 = ROTL(x1, 17); x1 ^= x0;
    x0 += x1; x1 = ROTL(x1, 29); x1 ^= x0;
    x0 += x1; x1 = ROTL(x1, 16); x1 ^= x0;
    x0 += x1; x1 = ROTL(x1, 24); x1 ^= x0;
    x0 += ks2; x1 += ks0 + 2u;
    // rounds 9-12: rot [13,15,26,6]
    x0 += x1; x1 = ROTL(x1, 13); x1 ^= x0;
    x0 += x1; x1 = ROTL(x1, 15); x1 ^= x0;
    x0 += x1; x1 = ROTL(x1, 26); x1 ^= x0;
    x0 += x1; x1 = ROTL(x1,  6); x1 ^= x0;
    x0 += ks0; x1 += ks1 + 3u;
    // rounds 13-16: rot [17,29,16,24]
    x0 += x1; x1 = ROTL(x1, 17); x1 ^= x0;
    x0 += x1; x1 = ROTL(x1, 29); x1 ^= x0;
    x0 += x1; x1 = ROTL(x1, 16); x1 ^= x0;
    x0 += x1; x1 = ROTL(x1, 24); x1 ^= x0;
    x0 += ks1; x1 += ks2 + 4u;
    // rounds 17-20: rot [13,15,26,6]
    x0 += x1; x1 = ROTL(x1, 13); x1 ^= x0;
    x0 += x1; x1 = ROTL(x1, 15); x1 ^= x0;
    x0 += x1; x1 = ROTL(x1, 26); x1 ^= x0;
    x0 += x1; x1 = ROTL(x1,  6); x1 ^= x0;
    x0 += ks2; x1 += ks0 + 5u;
    return x0 ^ x1;   // partitionable 32-bit path: bits = o0 ^ o1
}

__global__ __launch_bounds__(256) void BiasedFeatureDropout_kernel(
        const v4f* __restrict__ x, v4f* __restrict__ out, uint32_t half4) {
    uint32_t t = blockIdx.x * 256u + threadIdx.x;
    if (t >= half4) return;

    const uint32_t CHW   = 802816u;   // 256*56*56
    const uint32_t BIASE = 100352u;   // 32*56*56

    uint32_t base = t * 4u;
    // second float4 sits at element offset half4*4 = 25690112 = 32*CHW
    // -> same remainder mod CHW -> same channel class -> ONE threshold
    uint32_t rem = base % CHW;
    uint32_t T = (rem < BIASE) ? (1677722u << 9) : (6710887u << 9);

    // issue both loads up front; threefry depends only on the index,
    // so ~1100 cycles of integer compute hide the HBM latency
    v4f a = x[t];
    v4f b = x[t + half4];
    uint32_t c2 = base + half4 * 4u;

    uint32_t bitsA[4], bitsB[4];
    #pragma unroll
    for (int k = 0; k < 4; ++k) bitsA[k] = threefry_bits(base + (uint32_t)k);
    #pragma unroll
    for (int k = 0; k < 4; ++k) bitsB[k] = threefry_bits(c2 + (uint32_t)k);

    v4f oa, ob;
    #pragma unroll
    for (int k = 0; k < 4; ++k) {
        oa[k] = (bitsA[k] < T) ? a[k] * 1.25f : 0.0f;
        ob[k] = (bitsB[k] < T) ? b[k] * 1.25f : 0.0f;
    }
    __builtin_nontemporal_store(oa, &out[t]);
    __builtin_nontemporal_store(ob, &out[t + half4]);
}

extern "C" void kernel_launch(void* const* d_in, const int* in_sizes, int n_in,
                              void* d_out, int out_size, void* d_ws, size_t ws_size,
                              hipStream_t stream) {
    const float* x = (const float*)d_in[0];
    float* out = (float*)d_out;
    uint32_t n = (uint32_t)out_size;   // 51,380,224
    uint32_t half4 = n / 8u;           // 6,422,528 float4s per half
    int block = 256;
    int grid = (int)((half4 + block - 1) / block);   // 25088
    BiasedFeatureDropout_kernel<<<grid, block, 0, stream>>>(
        (const v4f*)x, (v4f*)out, half4);
}